// Round 12
// baseline (181.853 us; speedup 1.0000x reference)
//
#include <hip/hip_runtime.h>
#include <math.h>

typedef unsigned int u32;
typedef unsigned long long u64;
typedef unsigned short u16;

constexpr int NB   = 32;     // batch
constexpr int NN   = 50000;  // boxes per image
constexpr int NC   = 10;     // classes
constexpr int KK   = 512;    // PRE_NMS_TOPK
constexpr int MAXD = 100;    // MAX_DETECTIONS
constexpr int CAP  = 2048;   // per-(b,c) candidate list capacity (expect ~705)
constexpr int LCAP = 192;    // per-class per-block LDS staging (expect ~28)

// output section offsets (floats)
constexpr int OFF_BOX = 0;
constexpr int OFF_SC  = NB * MAXD * 4;
constexpr int OFF_LB  = OFF_SC + NB * MAXD;
constexpr int OFF_RT  = OFF_LB + NB * MAXD;
constexpr int OFF_TR  = OFF_RT + NB * MAXD * 3;

__device__ __forceinline__ u32 ord_f32(float s) {
  u32 u = __float_as_uint(s);
  return (u & 0x80000000u) ? ~u : (u | 0x80000000u);
}
__device__ __forceinline__ float unord_f32(u32 o) {
  u32 u = (o & 0x80000000u) ? (o & 0x7FFFFFFFu) : ~o;
  return __uint_as_float(u);
}
// key: high 32 = ordered masked score, low 32 = ~idx (ties -> lower idx wins)
__device__ __forceinline__ u64 make_key(float s, u32 i) {
  float sp = (s > 0.01f) ? s : -INFINITY;
  return ((u64)ord_f32(sp) << 32) | (u64)(u32)(~i);
}
// linear-quantized monotone digest bin (8-bit): uniform scores -> uniform bins
__device__ __forceinline__ u32 bin8(float x) {
  if (!(x > 0.01f)) return 0;           // invalid -> bin 0
  u32 q = (u32)(x * 65536.0f);          // RN mul + trunc cvt: monotone
  q = q > 65535u ? 65535u : q;
  return q >> 8;                        // valid -> bin >= 2
}

// ---------- K0: zero ghist + gcnt ----------
__global__ __launch_bounds__(512) void init_kernel(u32* __restrict__ ghist,
                                                   u32* __restrict__ gcnt) {
  const int i = blockIdx.x * 512 + threadIdx.x;
  if (i < NB * NC * 256) ghist[i] = 0;
  if (i < NB * NC) gcnt[i] = 0;
}

// ---------- K1: per-(b,c) 256-bin digest histogram (coalesced cls read) ----
__global__ __launch_bounds__(512) void hist_kernel(
    const float* __restrict__ cls, u32* __restrict__ ghist) {
  const int blk = blockIdx.x;               // 320 = 32 images x 10 segments
  const int b = blk / 10, seg = blk % 10;   // segment = 5000 rows
  const float* src = cls + (size_t)b * NN * NC + (size_t)seg * 50000;
  __shared__ u32 chist[NC * 256];
  const int t = threadIdx.x;
  for (int i = t; i < NC * 256; i += 512) chist[i] = 0;
  __syncthreads();
  for (int q = t; q < 12500; q += 512) {
    float4 v = ((const float4*)src)[q];
    float arr[4] = {v.x, v.y, v.z, v.w};
#pragma unroll
    for (int k = 0; k < 4; ++k) {
      int e = q * 4 + k;
      int c = e % 10;
      atomicAdd(&chist[c * 256 + bin8(arr[k])], 1u);
    }
  }
  __syncthreads();
  for (int i = t; i < NC * 256; i += 512) {
    u32 v = chist[i];
    if (v) atomicAdd(&ghist[(size_t)(b * NC + (i >> 8)) * 256 + (i & 255)], v);
  }
}

// ---------- K2: per-(b,c) coarse threshold c* from the 256-bin hist ----------
__global__ __launch_bounds__(64) void cstar_kernel(
    const u32* __restrict__ ghist, u32* __restrict__ cstar) {
  const int bc = blockIdx.x;
  const int lane = threadIdx.x;
  const u32* gh = ghist + (size_t)bc * 256;
  u32 h[4], csum = 0;
#pragma unroll
  for (int k = 0; k < 4; ++k) { h[k] = gh[lane * 4 + k]; csum += h[k]; }
  u32 incl = csum;  // inclusive suffix over lanes (bin-group ascending)
#pragma unroll
  for (int s = 1; s < 64; s <<= 1) {
    u32 o = __shfl_down(incl, s, 64);
    if (lane + s < 64) incl += o;
  }
  u32 run = incl - csum;  // count of digests in bins strictly above this group
  int dloc = -1;
#pragma unroll
  for (int k = 3; k >= 0; --k) {  // bins lane*4+3 .. lane*4+0, descending
    int bin = lane * 4 + k;
    if (bin >= 1 && run < (u32)KK && run + h[k] >= (u32)KK) dloc = bin;
    run += h[k];
  }
  u64 m = __ballot(dloc >= 0);
  int d = 1;  // fallback: fewer than 512 valid -> take all valid
  if (m) d = __shfl(dloc, (int)__builtin_ctzll(m), 64);
  if (lane == 0) cstar[bc] = (u32)d;
}

// ---------- K3: gather exact keys (bin >= c*), LDS-staged appends ----------
__global__ __launch_bounds__(512) void gather_kernel(
    const float* __restrict__ cls, const u32* __restrict__ cstar,
    u64* __restrict__ glist, u32* __restrict__ gcnt) {
  const int blk = blockIdx.x;              // 800 = 32 images x 25 chunks
  const int b = blk / 25, ch = blk % 25;   // chunk = 2000 rows = 20000 floats
  const float* src = cls + (size_t)b * NN * NC + (size_t)ch * 20000;
  __shared__ u32 cs[NC];
  __shared__ u32 lcnt[NC];
  __shared__ u32 lbase[NC];
  __shared__ u64 lbuf[NC][LCAP];           // 15 KiB staging
  const int t = threadIdx.x;
  if (t < NC) { cs[t] = cstar[b * NC + t]; lcnt[t] = 0; }
  __syncthreads();
  for (int q = t; q < 5000; q += 512) {
    float4 v = ((const float4*)src)[q];
    float arr[4] = {v.x, v.y, v.z, v.w};
#pragma unroll
    for (int k = 0; k < 4; ++k) {
      int e = q * 4 + k;
      int c = e % 10;
      float x = arr[k];
      if (bin8(x) >= cs[c]) {
        u32 idx = (u32)((ch * 20000 + e) / 10);
        u32 p = atomicAdd(&lcnt[c], 1u);
        if (p < (u32)LCAP) {
          lbuf[c][p] = make_key(x, idx);
        } else {  // overflow fallback (correct for any data): direct global
          u32 g = atomicAdd(&gcnt[b * NC + c], 1u);
          if (g < (u32)CAP) glist[(size_t)(b * NC + c) * CAP + g] = make_key(x, idx);
        }
      }
    }
  }
  __syncthreads();
  if (t < NC) {  // one ranged reservation per class per block (10 atomics)
    u32 n = min(lcnt[t], (u32)LCAP);
    lbase[t] = atomicAdd(&gcnt[b * NC + t], n);
  }
  __syncthreads();
  for (int c = 0; c < NC; ++c) {  // coalesced flush
    u32 n = min(lcnt[c], (u32)LCAP);
    u32 base = lbase[c];
    for (u32 i = t; i < n; i += 512) {
      u32 p = base + i;
      if (p < (u32)CAP) glist[(size_t)(b * NC + c) * CAP + p] = lbuf[c][i];
    }
  }
}

// ---------- K4: per-(b,c) register-tiled rank-sort + greedy NMS ----------
__global__ __launch_bounds__(256) void selnms_kernel(
    const u64* __restrict__ glist, const u32* __restrict__ gcnt,
    const float* __restrict__ boxes, int* __restrict__ tidx,
    float* __restrict__ ksc) {
  const int bc = blockIdx.x;
  const int b = bc / NC;
  __shared__ __align__(16) u64 cand[CAP + 2];  // +2 zero pad for b128 reads
  __shared__ u64 sel[KK];                  // 4 KiB
  __shared__ float4 bx4[KK];               // 8 KiB
  __shared__ float ars[KK];                // 2 KiB
  __shared__ u64 kmask[8];
  __shared__ int s_cnt;
  const int t = threadIdx.x;               // 256 threads = 4 waves
  const int lane = t & 63, wv = t >> 6;

  if (t == 0) s_cnt = (int)gcnt[bc];
  sel[t] = make_key(-INFINITY, 0);         // prefill both halves
  sel[t + 256] = make_key(-INFINITY, 0);
  __syncthreads();
  const int M = min(s_cnt, CAP);    // expect ~705
  for (int i = t; i < M; i += 256) cand[i] = glist[(size_t)bc * CAP + i];
  if (t < 2) cand[M + t] = 0;       // pad (real keys have top bit set -> > 0)
  __syncthreads();

  // register-tiled rank-sort: thread owns keys {t, t+256, ...}; one b128 LDS
  // read serves 2 j-keys vs all owned keys (rule #20: k statically unrolled)
  {
    u64 myk[8];
    int rank[8];
#pragma unroll
    for (int k = 0; k < 8; ++k) {
      int i = t + k * 256;
      myk[k] = (i < M) ? cand[i] : ~0ull;
      rank[k] = 0;
    }
    const int Mp = (M + 1) & ~1;  // even bound (covers pad)
    for (int j = 0; j < Mp; j += 2) {
      const ulonglong2 v = *(const ulonglong2*)&cand[j];
#pragma unroll
      for (int k = 0; k < 8; ++k) {
        if (k * 256 < M) {  // uniform per unrolled copy
          rank[k] += (v.x > myk[k]) ? 1 : 0;
          rank[k] += (v.y > myk[k]) ? 1 : 0;
        }
      }
    }
#pragma unroll
    for (int k = 0; k < 8; ++k) {
      int i = t + k * 256;
      if (i < M && rank[k] < KK) sel[rank[k]] = myk[k];
    }
  }
  __syncthreads();

#pragma unroll
  for (int h = 0; h < 2; ++h) {  // slots t and t+256
    const int s = h * 256 + t;
    const u64 k = sel[s];
    const int idx = (int)(~(u32)k);
    tidx[bc * KK + s] = idx;
    const float4 bx = *(const float4*)(boxes + ((size_t)b * NN + idx) * 4);
    bx4[s] = bx;
    ars[s] = (bx.z - bx.x) * (bx.w - bx.y);
  }
  __syncthreads();

  if (wv == 0) {  // greedy walk: on-demand rows, all state in registers
    float jx1[8], jy1[8], jx2[8], jy2[8], jar[8];
    u64 vw_[8], sup[8], kw[8];
#pragma unroll
    for (int q = 0; q < 8; ++q) {
      const int j = q * 64 + lane;
      float4 bb = bx4[j];
      jx1[q] = bb.x; jy1[q] = bb.y; jx2[q] = bb.z; jy2[q] = bb.w;
      jar[q] = ars[j];
      float sc = unord_f32((u32)(sel[j] >> 32));
      vw_[q] = __ballot(sc > 0.01f);
      sup[q] = 0;
      kw[q] = 0;
    }
    // RN32(inter/uni) > 0.5  <=>  inter/uni > 0.5 + 2^-25 (tie->even = 0.5);
    // sign(inter - C*uni) exact via one f64 fma (50-bit product <= 53 bits)
    const double C = 0x1.000001p-1;
    int count = 0;
    bool done = false;
#pragma unroll
    for (int w = 0; w < 8; ++w) {  // w compile-time in each unrolled copy
      if (!done) {
        u64 av = vw_[w] & ~sup[w];
        while (av) {
          const int bbit = (int)__builtin_ctzll(av);
          const int i = w * 64 + bbit;
          kw[w] |= 1ull << bbit;
          if (++count == MAXD) { done = true; break; }
          // one broadcast LDS read pair (all lanes same addr): short chain
          const float4 bi = bx4[i];
          const float ai = ars[i];
#pragma unroll
          for (int q = 0; q < 8; ++q) {
            if (q >= w) {  // only undecided words
              float ix1 = fmaxf(bi.x, jx1[q]);
              float iy1 = fmaxf(bi.y, jy1[q]);
              float ix2 = fminf(bi.z, jx2[q]);
              float iy2 = fminf(bi.w, jy2[q]);
              float iw = fmaxf(ix2 - ix1, 0.0f);
              float ih = fmaxf(iy2 - iy1, 0.0f);
              float inter = iw * ih;
              float uni = ai + jar[q] - inter;
              bool s = (uni > 0.0f) && (fma(-C, (double)uni, (double)inter) > 0.0);
              sup[q] |= __ballot(s);
            }
          }
          const u64 mask_gt = (bbit == 63) ? 0ull : (~0ull << (bbit + 1));
          av = vw_[w] & ~sup[w] & mask_gt;
        }
      }
    }
    if (lane < 8) {  // publish keep words (static selection, rule #20)
      u64 word = kw[0];
#pragma unroll
      for (int q = 1; q < 8; ++q) word = (lane == q) ? kw[q] : word;
      kmask[lane] = word;
    }
  }
  __syncthreads();
#pragma unroll
  for (int h = 0; h < 2; ++h) {
    const int s = h * 256 + t;
    float sc = unord_f32((u32)(sel[s] >> 32));
    bool keep = (kmask[s >> 6] >> (s & 63)) & 1ull;
    ksc[bc * KK + s] = keep ? sc : -INFINITY;
  }
}

// ------- K5: per-image top-100 (register-tiled rank-sort) + gather ---------
__global__ __launch_bounds__(512) void final_kernel(
    const float* __restrict__ boxes, const float* __restrict__ rot,
    const float* __restrict__ trans, const int* __restrict__ tidx,
    const float* __restrict__ ksc, float* __restrict__ out) {
  const int b = blockIdx.x;
  __shared__ __align__(16) u64 ck[1024 + 2];
  __shared__ u64 top[MAXD];
  __shared__ int cnt;
  const int t = threadIdx.x;
  if (t == 0) cnt = 0;
  if (t < MAXD) top[t] = make_key(-INFINITY, 0);
  __syncthreads();
  for (int j = t; j < NC * KK; j += 512) {
    float s = ksc[b * NC * KK + j];
    if (s != -INFINITY) {
      int p = atomicAdd(&cnt, 1);
      if (p < 1024) ck[p] = ((u64)ord_f32(s) << 32) | (u64)(u32)(~(u32)j);
    }
  }
  __syncthreads();
  const int n = min(cnt, 1024);  // <= 1000 by construction
  if (t < 2) ck[n + t] = 0;      // pad
  __syncthreads();
  {
    u64 myk[2];
    int rank[2];
#pragma unroll
    for (int k = 0; k < 2; ++k) {
      int i = t + k * 512;
      myk[k] = (i < n) ? ck[i] : ~0ull;
      rank[k] = 0;
    }
    const int np = (n + 1) & ~1;
    for (int j = 0; j < np; j += 2) {
      const ulonglong2 v = *(const ulonglong2*)&ck[j];
#pragma unroll
      for (int k = 0; k < 2; ++k) {
        if (k * 512 < n) {
          rank[k] += (v.x > myk[k]) ? 1 : 0;
          rank[k] += (v.y > myk[k]) ? 1 : 0;
        }
      }
    }
#pragma unroll
    for (int k = 0; k < 2; ++k) {
      int i = t + k * 512;
      if (i < n && rank[k] < MAXD) top[rank[k]] = myk[k];
    }
  }
  __syncthreads();

  if (t < MAXD) {
    float b0 = -1.f, b1 = -1.f, b2 = -1.f, b3 = -1.f;
    float os = -1.f, ol = -1.f;
    float r0 = -1.f, r1 = -1.f, r2 = -1.f;
    float t0 = -1.f, t1 = -1.f, t2 = -1.f;
    const u64 k = top[t];
    const float sc = unord_f32((u32)(k >> 32));
    if (sc != -INFINITY) {  // valid (reference: isfinite)
      int j = (int)(~(u32)k);
      int c = j >> 9, slot = j & (KK - 1);
      int idx = tidx[(b * NC + c) * KK + slot];
      os = sc;
      ol = (float)c;
      const float4 bx = *(const float4*)(boxes + ((size_t)b * NN + idx) * 4);
      b0 = bx.x; b1 = bx.y; b2 = bx.z; b3 = bx.w;
      const float* rp = rot + ((size_t)b * NN + idx) * 3;
      r0 = rp[0]; r1 = rp[1]; r2 = rp[2];
      const float* tp = trans + ((size_t)b * NN + idx) * 3;
      t0 = tp[0]; t1 = tp[1]; t2 = tp[2];
    }
    const int o = b * MAXD + t;
    out[OFF_BOX + (size_t)o * 4 + 0] = b0;
    out[OFF_BOX + (size_t)o * 4 + 1] = b1;
    out[OFF_BOX + (size_t)o * 4 + 2] = b2;
    out[OFF_BOX + (size_t)o * 4 + 3] = b3;
    out[OFF_SC + o] = os;
    out[OFF_LB + o] = ol;
    out[OFF_RT + (size_t)o * 3 + 0] = r0;
    out[OFF_RT + (size_t)o * 3 + 1] = r1;
    out[OFF_RT + (size_t)o * 3 + 2] = r2;
    out[OFF_TR + (size_t)o * 3 + 0] = t0;
    out[OFF_TR + (size_t)o * 3 + 1] = t1;
    out[OFF_TR + (size_t)o * 3 + 2] = t2;
  }
}

extern "C" void kernel_launch(void* const* d_in, const int* in_sizes, int n_in,
                              void* d_out, int out_size, void* d_ws, size_t ws_size,
                              hipStream_t stream) {
  const float* boxes = (const float*)d_in[0];
  const float* cls   = (const float*)d_in[1];
  const float* rot   = (const float*)d_in[2];
  const float* trans = (const float*)d_in[3];
  float* out = (float*)d_out;

  u64* glist = (u64*)d_ws;                              // 5.24 MB
  int* tidx  = (int*)(glist + (size_t)NB * NC * CAP);   // 640 KB
  float* ksc = (float*)(tidx + NB * NC * KK);           // 640 KB
  u32* ghist = (u32*)(ksc + NB * NC * KK);              // 320 KB
  u32* gcnt  = ghist + NB * NC * 256;                   // 1.3 KB
  u32* cstar = gcnt + NB * NC;                          // 1.3 KB

  init_kernel<<<161, 512, 0, stream>>>(ghist, gcnt);
  hist_kernel<<<NB * 10, 512, 0, stream>>>(cls, ghist);
  cstar_kernel<<<NB * NC, 64, 0, stream>>>(ghist, cstar);
  gather_kernel<<<NB * 25, 512, 0, stream>>>(cls, cstar, glist, gcnt);
  selnms_kernel<<<NB * NC, 256, 0, stream>>>(glist, gcnt, boxes, tidx, ksc);
  final_kernel<<<NB, 512, 0, stream>>>(boxes, rot, trans, tidx, ksc, out);
}

// Round 13
// 143.190 us; speedup vs baseline: 1.2700x; 1.2700x over previous
//
#include <hip/hip_runtime.h>
#include <math.h>

typedef unsigned int u32;
typedef unsigned long long u64;

constexpr int NB   = 32;     // batch
constexpr int NN   = 50000;  // boxes per image
constexpr int NC   = 10;     // classes
constexpr int KK   = 512;    // PRE_NMS_TOPK
constexpr int MAXD = 100;    // MAX_DETECTIONS
constexpr int CAP  = 2048;   // per-(b,c) candidate list capacity
constexpr int LCAP = 192;    // per-class per-block LDS staging (expect ~39)
constexpr int GCH  = 2500;   // rows per gather chunk (50000 = 20*2500)
constexpr int KMAX = 1024;   // compile-time sort bound (expect M ~781)
constexpr u32 TBIN = 252;    // digest-bin threshold: x >~ 0.984375 -> ~781/class

// output section offsets (floats)
constexpr int OFF_BOX = 0;
constexpr int OFF_SC  = NB * MAXD * 4;
constexpr int OFF_LB  = OFF_SC + NB * MAXD;
constexpr int OFF_RT  = OFF_LB + NB * MAXD;
constexpr int OFF_TR  = OFF_RT + NB * MAXD * 3;

__device__ __forceinline__ u32 ord_f32(float s) {
  u32 u = __float_as_uint(s);
  return (u & 0x80000000u) ? ~u : (u | 0x80000000u);
}
__device__ __forceinline__ float unord_f32(u32 o) {
  u32 u = (o & 0x80000000u) ? (o & 0x7FFFFFFFu) : ~o;
  return __uint_as_float(u);
}
// key: high 32 = ordered masked score, low 32 = ~idx (ties -> lower idx wins)
__device__ __forceinline__ u64 make_key(float s, u32 i) {
  float sp = (s > 0.01f) ? s : -INFINITY;
  return ((u64)ord_f32(sp) << 32) | (u64)(u32)(~i);
}
// linear-quantized monotone 16-bit digest (0 = invalid)
__device__ __forceinline__ u32 digest16(float x) {
  if (!(x > 0.01f)) return 0;
  u32 q = (u32)(x * 65536.0f);
  return q > 65535u ? 65535u : q;
}

// ---------- K1: single-pass gather, fixed threshold, LDS-staged ----------
__global__ __launch_bounds__(512) void gather_kernel(
    const float* __restrict__ cls, u64* __restrict__ glist,
    u32* __restrict__ gcnt) {
  const int blk = blockIdx.x;              // 640 = 32 images x 20 chunks
  const int b = blk / 20, ch = blk % 20;   // chunk = 2500 rows = 25000 floats
  const float* src = cls + (size_t)b * NN * NC + (size_t)ch * GCH * NC;
  __shared__ u32 lcnt[NC];
  __shared__ u32 lbase[NC];
  __shared__ u64 lbuf[NC][LCAP];           // 15 KiB staging
  const int t = threadIdx.x;
  if (t < NC) lcnt[t] = 0;
  __syncthreads();
  for (int q = t; q < GCH * NC / 4; q += 512) {
    float4 v = ((const float4*)src)[q];
    float arr[4] = {v.x, v.y, v.z, v.w};
#pragma unroll
    for (int k = 0; k < 4; ++k) {
      int e = q * 4 + k;
      int c = e % 10;
      float x = arr[k];
      if ((digest16(x) >> 8) >= TBIN) {
        u32 idx = (u32)((ch * (GCH * NC) + e) / 10);
        u32 p = atomicAdd(&lcnt[c], 1u);
        if (p < (u32)LCAP) {
          lbuf[c][p] = make_key(x, idx);
        } else {  // staging overflow fallback: direct global append
          u32 g = atomicAdd(&gcnt[b * NC + c], 1u);
          if (g < (u32)CAP) glist[(size_t)(b * NC + c) * CAP + g] = make_key(x, idx);
        }
      }
    }
  }
  __syncthreads();
  if (t < NC) {  // one ranged reservation per class per block
    u32 n = min(lcnt[t], (u32)LCAP);
    lbase[t] = atomicAdd(&gcnt[b * NC + t], n);
  }
  __syncthreads();
  for (int c = 0; c < NC; ++c) {  // coalesced flush
    u32 n = min(lcnt[c], (u32)LCAP);
    u32 base = lbase[c];
    for (u32 i = t; i < n; i += 512) {
      u32 p = base + i;
      if (p < (u32)CAP) glist[(size_t)(b * NC + c) * CAP + p] = lbuf[c][i];
    }
  }
}

// ---------- K2: repair (exactness guard; no-op when count in [512,1024]) ----
__global__ __launch_bounds__(512) void repair_kernel(
    const float* __restrict__ cls, u64* __restrict__ glist,
    u32* __restrict__ gcnt) {
  const int bc = blockIdx.x;
  const u32 n0 = gcnt[bc];
  if (n0 >= (u32)KK && n0 <= (u32)KMAX) return;  // normal path: exit
  // rare path: self-contained exact re-selection via 12-bit digest histogram
  const int b = bc / NC, c = bc % NC;
  const float* sbase = cls + (size_t)b * NN * NC + c;
  __shared__ u32 hist[4096];
  __shared__ u32 s_d;
  const int t = threadIdx.x;
  for (int i = t; i < 4096; i += 512) hist[i] = 0;
  __syncthreads();
  for (int i = t; i < NN; i += 512)
    atomicAdd(&hist[digest16(sbase[(size_t)i * NC]) >> 4], 1u);
  __syncthreads();
  if (t == 0) {
    u32 run = 0, d = 1;
    for (int i = 4095; i >= 1; --i) {
      run += hist[i];
      if (run >= (u32)KK) { d = (u32)i; break; }
      d = 1;
    }
    s_d = d;
    gcnt[bc] = 0;
  }
  __syncthreads();
  const u32 dstar = s_d;
  for (int i = t; i < NN; i += 512) {
    float x = sbase[(size_t)i * NC];
    u32 dg = digest16(x) >> 4;
    if (dg >= dstar && dg >= 1) {
      u32 p = atomicAdd(&gcnt[bc], 1u);
      if (p < (u32)CAP) glist[(size_t)bc * CAP + p] = make_key(x, (u32)i);
    }
  }
}

// ---------- K3: per-(b,c) branch-free rank-sort top-512 + greedy NMS ----------
__global__ __launch_bounds__(256) void selnms_kernel(
    const u64* __restrict__ glist, const u32* __restrict__ gcnt,
    const float* __restrict__ boxes, int* __restrict__ tidx,
    float* __restrict__ ksc) {
  const int bc = blockIdx.x;
  const int b = bc / NC;
  __shared__ __align__(16) u64 cand[KMAX];  // 8 KiB
  __shared__ u64 sel[KK];                   // 4 KiB
  __shared__ float4 bx4[KK];                // 8 KiB
  __shared__ float ars[KK];                 // 2 KiB
  __shared__ u64 kmask[8];
  const int t = threadIdx.x;                // 256 threads = 4 waves
  const int lane = t & 63, wv = t >> 6;

  const int M = min((int)gcnt[bc], KMAX);
  // fill: real keys then distinct tiny pads ((u64)i < any real key)
  for (int i = t; i < KMAX; i += 256)
    cand[i] = (i < M) ? glist[(size_t)bc * CAP + i] : (u64)i;
  sel[t] = make_key(-INFINITY, 0);
  sel[t + 256] = make_key(-INFINITY, 0);
  __syncthreads();

  // branch-free register-tiled rank-sort over compile-time KMAX keys
  {
    u64 myk[4];
    int rank[4];
#pragma unroll
    for (int k = 0; k < 4; ++k) { myk[k] = cand[t + k * 256]; rank[k] = 0; }
    for (int j = 0; j < KMAX; j += 2) {
      const ulonglong2 v = *(const ulonglong2*)&cand[j];
#pragma unroll
      for (int k = 0; k < 4; ++k) {
        rank[k] += (v.x > myk[k]) ? 1 : 0;
        rank[k] += (v.y > myk[k]) ? 1 : 0;
      }
    }
#pragma unroll
    for (int k = 0; k < 4; ++k) {
      int i = t + k * 256;
      if (i < M && rank[k] < KK) sel[rank[k]] = myk[k];
    }
  }
  __syncthreads();

#pragma unroll
  for (int h = 0; h < 2; ++h) {  // slots t and t+256
    const int s = h * 256 + t;
    const u64 k = sel[s];
    const int idx = (int)(~(u32)k);
    tidx[bc * KK + s] = idx;
    const float4 bx = *(const float4*)(boxes + ((size_t)b * NN + idx) * 4);
    bx4[s] = bx;
    ars[s] = (bx.z - bx.x) * (bx.w - bx.y);
  }
  __syncthreads();

  if (wv == 0) {  // greedy walk: on-demand rows, all state in registers
    float jx1[8], jy1[8], jx2[8], jy2[8], jar[8];
    u64 vw_[8], sup[8], kw[8];
#pragma unroll
    for (int q = 0; q < 8; ++q) {
      const int j = q * 64 + lane;
      float4 bb = bx4[j];
      jx1[q] = bb.x; jy1[q] = bb.y; jx2[q] = bb.z; jy2[q] = bb.w;
      jar[q] = ars[j];
      float sc = unord_f32((u32)(sel[j] >> 32));
      vw_[q] = __ballot(sc > 0.01f);
      sup[q] = 0;
      kw[q] = 0;
    }
    // RN32(inter/uni) > 0.5  <=>  inter/uni > 0.5+2^-25
    //   <=>  (inter - 0.5f*uni) > uni*2^-25f   [all-f32 EXACT:
    //   0.5*uni exact scale; inter-uni/2 exact by Sterbenz when
    //   inter >= uni/2 (inter <= uni always); sign preserved otherwise;
    //   uni*2^-25 exact scale, uni >= 1 so no subnormals]
    int count = 0;
    bool done = false;
#pragma unroll
    for (int w = 0; w < 8; ++w) {  // w compile-time in each unrolled copy
      if (!done) {
        u64 av = vw_[w] & ~sup[w];
        while (av) {
          const int bbit = (int)__builtin_ctzll(av);
          const int i = w * 64 + bbit;
          kw[w] |= 1ull << bbit;
          if (++count == MAXD) { done = true; break; }
          const float4 bi = bx4[i];  // broadcast LDS read
          const float ai = ars[i];
#pragma unroll
          for (int q = 0; q < 8; ++q) {
            if (q >= w) {  // compile-time guard: only undecided words
              float ix1 = fmaxf(bi.x, jx1[q]);
              float iy1 = fmaxf(bi.y, jy1[q]);
              float ix2 = fminf(bi.z, jx2[q]);
              float iy2 = fminf(bi.w, jy2[q]);
              float iw = fmaxf(ix2 - ix1, 0.0f);
              float ih = fmaxf(iy2 - iy1, 0.0f);
              float inter = iw * ih;
              float uni = ai + jar[q] - inter;
              bool s = (uni > 0.0f) && ((inter - 0.5f * uni) > uni * 0x1p-25f);
              sup[q] |= __ballot(s);
            }
          }
          const u64 mask_gt = (bbit == 63) ? 0ull : (~0ull << (bbit + 1));
          av = vw_[w] & ~sup[w] & mask_gt;
        }
      }
    }
    if (lane < 8) {  // publish keep words (static selection, rule #20)
      u64 word = kw[0];
#pragma unroll
      for (int q = 1; q < 8; ++q) word = (lane == q) ? kw[q] : word;
      kmask[lane] = word;
    }
  }
  __syncthreads();
#pragma unroll
  for (int h = 0; h < 2; ++h) {
    const int s = h * 256 + t;
    float sc = unord_f32((u32)(sel[s] >> 32));
    bool keep = (kmask[s >> 6] >> (s & 63)) & 1ull;
    ksc[bc * KK + s] = keep ? sc : -INFINITY;
  }
}

// ------- K4: per-image top-100 (branch-free rank-sort) + gather ---------
__global__ __launch_bounds__(256) void final_kernel(
    const float* __restrict__ boxes, const float* __restrict__ rot,
    const float* __restrict__ trans, const int* __restrict__ tidx,
    const float* __restrict__ ksc, float* __restrict__ out) {
  const int b = blockIdx.x;
  __shared__ __align__(16) u64 ck[KMAX];
  __shared__ u64 top[MAXD];
  __shared__ int cnt;
  const int t = threadIdx.x;  // 256 threads
  if (t == 0) cnt = 0;
  if (t < MAXD) top[t] = make_key(-INFINITY, 0);
  for (int i = t; i < KMAX; i += 256) ck[i] = (u64)i;  // distinct tiny pads
  __syncthreads();
  for (int j = t; j < NC * KK; j += 256) {
    float s = ksc[b * NC * KK + j];
    if (s != -INFINITY) {
      int p = atomicAdd(&cnt, 1);
      if (p < KMAX) ck[p] = ((u64)ord_f32(s) << 32) | (u64)(u32)(~(u32)j);
    }
  }
  __syncthreads();
  const int n = min(cnt, KMAX);  // <= 1000 by construction
  {
    u64 myk[4];
    int rank[4];
#pragma unroll
    for (int k = 0; k < 4; ++k) { myk[k] = ck[t + k * 256]; rank[k] = 0; }
    for (int j = 0; j < KMAX; j += 2) {
      const ulonglong2 v = *(const ulonglong2*)&ck[j];
#pragma unroll
      for (int k = 0; k < 4; ++k) {
        rank[k] += (v.x > myk[k]) ? 1 : 0;
        rank[k] += (v.y > myk[k]) ? 1 : 0;
      }
    }
#pragma unroll
    for (int k = 0; k < 4; ++k) {
      int i = t + k * 256;
      if (i < n && rank[k] < MAXD) top[rank[k]] = myk[k];
    }
  }
  __syncthreads();

  if (t < MAXD) {
    float b0 = -1.f, b1 = -1.f, b2 = -1.f, b3 = -1.f;
    float os = -1.f, ol = -1.f;
    float r0 = -1.f, r1 = -1.f, r2 = -1.f;
    float t0 = -1.f, t1 = -1.f, t2 = -1.f;
    const u64 k = top[t];
    const float sc = unord_f32((u32)(k >> 32));
    if (sc != -INFINITY) {  // valid (reference: isfinite)
      int j = (int)(~(u32)k);
      int c = j >> 9, slot = j & (KK - 1);
      int idx = tidx[(b * NC + c) * KK + slot];
      os = sc;
      ol = (float)c;
      const float4 bx = *(const float4*)(boxes + ((size_t)b * NN + idx) * 4);
      b0 = bx.x; b1 = bx.y; b2 = bx.z; b3 = bx.w;
      const float* rp = rot + ((size_t)b * NN + idx) * 3;
      r0 = rp[0]; r1 = rp[1]; r2 = rp[2];
      const float* tp = trans + ((size_t)b * NN + idx) * 3;
      t0 = tp[0]; t1 = tp[1]; t2 = tp[2];
    }
    const int o = b * MAXD + t;
    out[OFF_BOX + (size_t)o * 4 + 0] = b0;
    out[OFF_BOX + (size_t)o * 4 + 1] = b1;
    out[OFF_BOX + (size_t)o * 4 + 2] = b2;
    out[OFF_BOX + (size_t)o * 4 + 3] = b3;
    out[OFF_SC + o] = os;
    out[OFF_LB + o] = ol;
    out[OFF_RT + (size_t)o * 3 + 0] = r0;
    out[OFF_RT + (size_t)o * 3 + 1] = r1;
    out[OFF_RT + (size_t)o * 3 + 2] = r2;
    out[OFF_TR + (size_t)o * 3 + 0] = t0;
    out[OFF_TR + (size_t)o * 3 + 1] = t1;
    out[OFF_TR + (size_t)o * 3 + 2] = t2;
  }
}

extern "C" void kernel_launch(void* const* d_in, const int* in_sizes, int n_in,
                              void* d_out, int out_size, void* d_ws, size_t ws_size,
                              hipStream_t stream) {
  const float* boxes = (const float*)d_in[0];
  const float* cls   = (const float*)d_in[1];
  const float* rot   = (const float*)d_in[2];
  const float* trans = (const float*)d_in[3];
  float* out = (float*)d_out;

  u64* glist = (u64*)d_ws;                              // 5.24 MB
  int* tidx  = (int*)(glist + (size_t)NB * NC * CAP);   // 640 KB
  float* ksc = (float*)(tidx + NB * NC * KK);           // 640 KB
  u32* gcnt  = (u32*)(ksc + NB * NC * KK);              // 1.3 KB

  hipMemsetAsync(gcnt, 0, NB * NC * sizeof(u32), stream);
  gather_kernel<<<NB * 20, 512, 0, stream>>>(cls, glist, gcnt);
  repair_kernel<<<NB * NC, 512, 0, stream>>>(cls, glist, gcnt);
  selnms_kernel<<<NB * NC, 256, 0, stream>>>(glist, gcnt, boxes, tidx, ksc);
  final_kernel<<<NB, 256, 0, stream>>>(boxes, rot, trans, tidx, ksc, out);
}

// Round 14
// 133.215 us; speedup vs baseline: 1.3651x; 1.0749x over previous
//
#include <hip/hip_runtime.h>
#include <math.h>

typedef unsigned int u32;
typedef unsigned long long u64;

constexpr int NB   = 32;     // batch
constexpr int NN   = 50000;  // boxes per image
constexpr int NC   = 10;     // classes
constexpr int KK   = 512;    // PRE_NMS_TOPK
constexpr int MAXD = 100;    // MAX_DETECTIONS
constexpr int CAP  = 2048;   // per-(b,c) candidate list capacity
constexpr int LCAP = 192;    // per-class per-block LDS staging (expect ~39)
constexpr int GCH  = 2500;   // rows per gather chunk (50000 = 20*2500)
constexpr int KMAX = 1024;   // compile-time sort bound (expect M ~781)
constexpr u32 TBIN = 252;    // digest-bin threshold: x >~ 0.984375 -> ~781/class

// output section offsets (floats)
constexpr int OFF_BOX = 0;
constexpr int OFF_SC  = NB * MAXD * 4;
constexpr int OFF_LB  = OFF_SC + NB * MAXD;
constexpr int OFF_RT  = OFF_LB + NB * MAXD;
constexpr int OFF_TR  = OFF_RT + NB * MAXD * 3;

__device__ __forceinline__ u32 ord_f32(float s) {
  u32 u = __float_as_uint(s);
  return (u & 0x80000000u) ? ~u : (u | 0x80000000u);
}
__device__ __forceinline__ float unord_f32(u32 o) {
  u32 u = (o & 0x80000000u) ? (o & 0x7FFFFFFFu) : ~o;
  return __uint_as_float(u);
}
// key: high 32 = ordered masked score, low 32 = ~idx (ties -> lower idx wins)
__device__ __forceinline__ u64 make_key(float s, u32 i) {
  float sp = (s > 0.01f) ? s : -INFINITY;
  return ((u64)ord_f32(sp) << 32) | (u64)(u32)(~i);
}
// linear-quantized monotone 16-bit digest (0 = invalid)
__device__ __forceinline__ u32 digest16(float x) {
  if (!(x > 0.01f)) return 0;
  u32 q = (u32)(x * 65536.0f);
  return q > 65535u ? 65535u : q;
}
// uniform-lane read of a float register (bbit is wave-uniform)
__device__ __forceinline__ float readlane_f(float v, int lane) {
  return __int_as_float(__builtin_amdgcn_readlane(__float_as_int(v), lane));
}

// ---------- K1: single-pass gather, fixed threshold, LDS-staged ----------
__global__ __launch_bounds__(512) void gather_kernel(
    const float* __restrict__ cls, u64* __restrict__ glist,
    u32* __restrict__ gcnt) {
  const int blk = blockIdx.x;              // 640 = 32 images x 20 chunks
  const int b = blk / 20, ch = blk % 20;   // chunk = 2500 rows = 25000 floats
  const float* src = cls + (size_t)b * NN * NC + (size_t)ch * GCH * NC;
  __shared__ u32 lcnt[NC];
  __shared__ u32 lbase[NC];
  __shared__ u64 lbuf[NC][LCAP];           // 15 KiB staging
  const int t = threadIdx.x;
  if (t < NC) lcnt[t] = 0;
  __syncthreads();
  for (int q = t; q < GCH * NC / 4; q += 512) {
    float4 v = ((const float4*)src)[q];
    float arr[4] = {v.x, v.y, v.z, v.w};
#pragma unroll
    for (int k = 0; k < 4; ++k) {
      int e = q * 4 + k;
      int c = e % 10;
      float x = arr[k];
      if ((digest16(x) >> 8) >= TBIN) {
        u32 idx = (u32)((ch * (GCH * NC) + e) / 10);
        u32 p = atomicAdd(&lcnt[c], 1u);
        if (p < (u32)LCAP) {
          lbuf[c][p] = make_key(x, idx);
        } else {  // staging overflow fallback: direct global append
          u32 g = atomicAdd(&gcnt[b * NC + c], 1u);
          if (g < (u32)CAP) glist[(size_t)(b * NC + c) * CAP + g] = make_key(x, idx);
        }
      }
    }
  }
  __syncthreads();
  if (t < NC) {  // one ranged reservation per class per block
    u32 n = min(lcnt[t], (u32)LCAP);
    lbase[t] = atomicAdd(&gcnt[b * NC + t], n);
  }
  __syncthreads();
  for (int c = 0; c < NC; ++c) {  // coalesced flush
    u32 n = min(lcnt[c], (u32)LCAP);
    u32 base = lbase[c];
    for (u32 i = t; i < n; i += 512) {
      u32 p = base + i;
      if (p < (u32)CAP) glist[(size_t)(b * NC + c) * CAP + p] = lbuf[c][i];
    }
  }
}

// ---------- K2: repair (exactness guard; no-op when count in [512,1024]) ----
__global__ __launch_bounds__(512) void repair_kernel(
    const float* __restrict__ cls, u64* __restrict__ glist,
    u32* __restrict__ gcnt) {
  const int bc = blockIdx.x;
  const u32 n0 = gcnt[bc];
  if (n0 >= (u32)KK && n0 <= (u32)KMAX) return;  // normal path: exit
  // rare path: self-contained exact re-selection via 12-bit digest histogram
  const int b = bc / NC, c = bc % NC;
  const float* sbase = cls + (size_t)b * NN * NC + c;
  __shared__ u32 hist[4096];
  __shared__ u32 s_d;
  const int t = threadIdx.x;
  for (int i = t; i < 4096; i += 512) hist[i] = 0;
  __syncthreads();
  for (int i = t; i < NN; i += 512)
    atomicAdd(&hist[digest16(sbase[(size_t)i * NC]) >> 4], 1u);
  __syncthreads();
  if (t == 0) {
    u32 run = 0, d = 1;
    for (int i = 4095; i >= 1; --i) {
      run += hist[i];
      if (run >= (u32)KK) { d = (u32)i; break; }
      d = 1;
    }
    s_d = d;
    gcnt[bc] = 0;
  }
  __syncthreads();
  const u32 dstar = s_d;
  for (int i = t; i < NN; i += 512) {
    float x = sbase[(size_t)i * NC];
    u32 dg = digest16(x) >> 4;
    if (dg >= dstar && dg >= 1) {
      u32 p = atomicAdd(&gcnt[bc], 1u);
      if (p < (u32)CAP) glist[(size_t)bc * CAP + p] = make_key(x, (u32)i);
    }
  }
}

// ---- K3: per-(b,c) wave-partitioned rank-sort top-512 + greedy NMS ----
__global__ __launch_bounds__(512) void selnms_kernel(
    const u64* __restrict__ glist, const u32* __restrict__ gcnt,
    const float* __restrict__ boxes, int* __restrict__ tidx,
    float* __restrict__ ksc) {
  const int bc = blockIdx.x;
  const int b = bc / NC;
  __shared__ __align__(16) u64 cand[KMAX];          // 8 KiB
  __shared__ __align__(16) ushort prank[KMAX][8];   // 16 KiB partial ranks
  __shared__ u64 sel[KK];                           // 4 KiB
  __shared__ float4 bx4[KK];                        // 8 KiB
  __shared__ float ars[KK];                         // 2 KiB
  __shared__ u64 kmask[8];
  const int t = threadIdx.x;                        // 512 threads = 8 waves
  const int lane = t & 63, wv = t >> 6;

  const int M = min((int)gcnt[bc], KMAX);
  // fill: real keys then distinct tiny pads ((u64)i < any real key, which
  // has bit63 set). Pads never out-rank real keys -> full fixed loops ok.
  for (int i = t; i < KMAX; i += 512)
    cand[i] = (i < M) ? glist[(size_t)bc * CAP + i] : (u64)i;
  sel[t] = make_key(-INFINITY, 0);
  __syncthreads();

  // Phase A: wave wv ranks ALL i against its j-slice [wv*128, wv*128+128)
  {
    u64 myk[16];
#pragma unroll
    for (int k = 0; k < 16; ++k) myk[k] = cand[lane + k * 64];
    int rnk[16];
#pragma unroll
    for (int k = 0; k < 16; ++k) rnk[k] = 0;
    const int j0 = wv * 128;
    for (int jj = 0; jj < 64; ++jj) {  // 64 broadcast b128 reads per wave
      const ulonglong2 v = *(const ulonglong2*)&cand[j0 + jj * 2];
#pragma unroll
      for (int k = 0; k < 16; ++k) {
        rnk[k] += (v.x > myk[k]) ? 1 : 0;
        rnk[k] += (v.y > myk[k]) ? 1 : 0;
      }
    }
#pragma unroll
    for (int k = 0; k < 16; ++k) prank[lane + k * 64][wv] = (ushort)rnk[k];
  }
  __syncthreads();
  // Phase B: sum 8 partials per i (one b128 read), scatter top-512
#pragma unroll
  for (int h = 0; h < 2; ++h) {
    const int i = h * 512 + t;
    const uint4 pv = *(const uint4*)&prank[i][0];
    const int r = (int)(pv.x & 0xFFFFu) + (int)(pv.x >> 16) +
                  (int)(pv.y & 0xFFFFu) + (int)(pv.y >> 16) +
                  (int)(pv.z & 0xFFFFu) + (int)(pv.z >> 16) +
                  (int)(pv.w & 0xFFFFu) + (int)(pv.w >> 16);
    if (i < M && r < KK) sel[r] = cand[i];
  }
  __syncthreads();

  {  // indices + box gather (one slot per thread)
    const u64 k = sel[t];
    const int idx = (int)(~(u32)k);
    tidx[bc * KK + t] = idx;
    const float4 bx = *(const float4*)(boxes + ((size_t)b * NN + idx) * 4);
    bx4[t] = bx;
    ars[t] = (bx.z - bx.x) * (bx.w - bx.y);
  }
  __syncthreads();

  if (wv == 0) {  // greedy walk: on-demand rows, all state in registers
    float jx1[8], jy1[8], jx2[8], jy2[8], jar[8];
    u64 vw_[8], sup[8], kw[8];
#pragma unroll
    for (int q = 0; q < 8; ++q) {
      const int j = q * 64 + lane;
      float4 bb = bx4[j];
      jx1[q] = bb.x; jy1[q] = bb.y; jx2[q] = bb.z; jy2[q] = bb.w;
      jar[q] = ars[j];
      float sc = unord_f32((u32)(sel[j] >> 32));
      vw_[q] = __ballot(sc > 0.01f);
      sup[q] = 0;
      kw[q] = 0;
    }
    // RN32(inter/uni) > 0.5  <=>  inter/uni > 0.5+2^-25
    //   <=>  (inter - 0.5f*uni) > uni*2^-25f   [all-f32 EXACT: 0.5*uni exact
    //   scale; inter-uni/2 exact by Sterbenz when inter >= uni/2 (inter <=
    //   uni always), sign preserved otherwise; uni*2^-25 exact scale]
    int count = 0;
    bool done = false;
#pragma unroll
    for (int w = 0; w < 8; ++w) {  // w compile-time in each unrolled copy
      if (!done) {
        u64 av = vw_[w] & ~sup[w];
        while (av) {
          const int bbit = (int)__builtin_ctzll(av);
          kw[w] |= 1ull << bbit;
          if (++count == MAXD) { done = true; break; }
          // box i = w*64+bbit lives in lane bbit of word-w registers;
          // bbit is wave-uniform -> 5 scalar readlanes (no LDS in chain)
          const float bix1 = readlane_f(jx1[w], bbit);
          const float biy1 = readlane_f(jy1[w], bbit);
          const float bix2 = readlane_f(jx2[w], bbit);
          const float biy2 = readlane_f(jy2[w], bbit);
          const float bia  = readlane_f(jar[w], bbit);
#pragma unroll
          for (int q = 0; q < 8; ++q) {
            if (q >= w) {  // compile-time guard: only undecided words
              float ix1 = fmaxf(bix1, jx1[q]);
              float iy1 = fmaxf(biy1, jy1[q]);
              float ix2 = fminf(bix2, jx2[q]);
              float iy2 = fminf(biy2, jy2[q]);
              float iw = fmaxf(ix2 - ix1, 0.0f);
              float ih = fmaxf(iy2 - iy1, 0.0f);
              float inter = iw * ih;
              float uni = bia + jar[q] - inter;
              bool s = (uni > 0.0f) && ((inter - 0.5f * uni) > uni * 0x1p-25f);
              sup[q] |= __ballot(s);
            }
          }
          const u64 mask_gt = (bbit == 63) ? 0ull : (~0ull << (bbit + 1));
          av = vw_[w] & ~sup[w] & mask_gt;
        }
      }
    }
    if (lane < 8) {  // publish keep words (static selection, rule #20)
      u64 word = kw[0];
#pragma unroll
      for (int q = 1; q < 8; ++q) word = (lane == q) ? kw[q] : word;
      kmask[lane] = word;
    }
  }
  __syncthreads();
  {
    const float sc = unord_f32((u32)(sel[t] >> 32));
    const bool keep = (kmask[t >> 6] >> (t & 63)) & 1ull;
    ksc[bc * KK + t] = keep ? sc : -INFINITY;
  }
}

// ---- K4: per-image top-100 (wave-partitioned rank-sort) + gather ----
__global__ __launch_bounds__(512) void final_kernel(
    const float* __restrict__ boxes, const float* __restrict__ rot,
    const float* __restrict__ trans, const int* __restrict__ tidx,
    const float* __restrict__ ksc, float* __restrict__ out) {
  const int b = blockIdx.x;
  __shared__ __align__(16) u64 ck[KMAX];
  __shared__ __align__(16) ushort prank[KMAX][8];
  __shared__ u64 top[MAXD];
  __shared__ int cnt;
  const int t = threadIdx.x;  // 512 threads = 8 waves
  const int lane = t & 63, wv = t >> 6;
  if (t == 0) cnt = 0;
  if (t < MAXD) top[t] = make_key(-INFINITY, 0);
  for (int i = t; i < KMAX; i += 512) ck[i] = (u64)i;  // distinct tiny pads
  __syncthreads();
  for (int j = t; j < NC * KK; j += 512) {
    float s = ksc[b * NC * KK + j];
    if (s != -INFINITY) {
      int p = atomicAdd(&cnt, 1);
      if (p < KMAX) ck[p] = ((u64)ord_f32(s) << 32) | (u64)(u32)(~(u32)j);
    }
  }
  __syncthreads();
  const int n = min(cnt, KMAX);  // <= 1000 by construction
  {
    u64 myk[16];
#pragma unroll
    for (int k = 0; k < 16; ++k) myk[k] = ck[lane + k * 64];
    int rnk[16];
#pragma unroll
    for (int k = 0; k < 16; ++k) rnk[k] = 0;
    const int j0 = wv * 128;
    for (int jj = 0; jj < 64; ++jj) {
      const ulonglong2 v = *(const ulonglong2*)&ck[j0 + jj * 2];
#pragma unroll
      for (int k = 0; k < 16; ++k) {
        rnk[k] += (v.x > myk[k]) ? 1 : 0;
        rnk[k] += (v.y > myk[k]) ? 1 : 0;
      }
    }
#pragma unroll
    for (int k = 0; k < 16; ++k) prank[lane + k * 64][wv] = (ushort)rnk[k];
  }
  __syncthreads();
#pragma unroll
  for (int h = 0; h < 2; ++h) {
    const int i = h * 512 + t;
    const uint4 pv = *(const uint4*)&prank[i][0];
    const int r = (int)(pv.x & 0xFFFFu) + (int)(pv.x >> 16) +
                  (int)(pv.y & 0xFFFFu) + (int)(pv.y >> 16) +
                  (int)(pv.z & 0xFFFFu) + (int)(pv.z >> 16) +
                  (int)(pv.w & 0xFFFFu) + (int)(pv.w >> 16);
    if (i < n && r < MAXD) top[r] = ck[i];
  }
  __syncthreads();

  if (t < MAXD) {
    float b0 = -1.f, b1 = -1.f, b2 = -1.f, b3 = -1.f;
    float os = -1.f, ol = -1.f;
    float r0 = -1.f, r1 = -1.f, r2 = -1.f;
    float t0 = -1.f, t1 = -1.f, t2 = -1.f;
    const u64 k = top[t];
    const float sc = unord_f32((u32)(k >> 32));
    if (sc != -INFINITY) {  // valid (reference: isfinite)
      int j = (int)(~(u32)k);
      int c = j >> 9, slot = j & (KK - 1);
      int idx = tidx[(b * NC + c) * KK + slot];
      os = sc;
      ol = (float)c;
      const float4 bx = *(const float4*)(boxes + ((size_t)b * NN + idx) * 4);
      b0 = bx.x; b1 = bx.y; b2 = bx.z; b3 = bx.w;
      const float* rp = rot + ((size_t)b * NN + idx) * 3;
      r0 = rp[0]; r1 = rp[1]; r2 = rp[2];
      const float* tp = trans + ((size_t)b * NN + idx) * 3;
      t0 = tp[0]; t1 = tp[1]; t2 = tp[2];
    }
    const int o = b * MAXD + t;
    out[OFF_BOX + (size_t)o * 4 + 0] = b0;
    out[OFF_BOX + (size_t)o * 4 + 1] = b1;
    out[OFF_BOX + (size_t)o * 4 + 2] = b2;
    out[OFF_BOX + (size_t)o * 4 + 3] = b3;
    out[OFF_SC + o] = os;
    out[OFF_LB + o] = ol;
    out[OFF_RT + (size_t)o * 3 + 0] = r0;
    out[OFF_RT + (size_t)o * 3 + 1] = r1;
    out[OFF_RT + (size_t)o * 3 + 2] = r2;
    out[OFF_TR + (size_t)o * 3 + 0] = t0;
    out[OFF_TR + (size_t)o * 3 + 1] = t1;
    out[OFF_TR + (size_t)o * 3 + 2] = t2;
  }
}

extern "C" void kernel_launch(void* const* d_in, const int* in_sizes, int n_in,
                              void* d_out, int out_size, void* d_ws, size_t ws_size,
                              hipStream_t stream) {
  const float* boxes = (const float*)d_in[0];
  const float* cls   = (const float*)d_in[1];
  const float* rot   = (const float*)d_in[2];
  const float* trans = (const float*)d_in[3];
  float* out = (float*)d_out;

  u64* glist = (u64*)d_ws;                              // 5.24 MB
  int* tidx  = (int*)(glist + (size_t)NB * NC * CAP);   // 640 KB
  float* ksc = (float*)(tidx + NB * NC * KK);           // 640 KB
  u32* gcnt  = (u32*)(ksc + NB * NC * KK);              // 1.3 KB

  hipMemsetAsync(gcnt, 0, NB * NC * sizeof(u32), stream);
  gather_kernel<<<NB * 20, 512, 0, stream>>>(cls, glist, gcnt);
  repair_kernel<<<NB * NC, 512, 0, stream>>>(cls, glist, gcnt);
  selnms_kernel<<<NB * NC, 512, 0, stream>>>(glist, gcnt, boxes, tidx, ksc);
  final_kernel<<<NB, 512, 0, stream>>>(boxes, rot, trans, tidx, ksc, out);
}